// Round 6
// baseline (119.685 us; speedup 1.0000x reference)
//
#include <hip/hip_runtime.h>
#include <math.h>

#define KOBJ 512
#define KTW 8               // packed row (32 B): xh[4] (8 fp16), s2, w_rep, w_att, pad
#define TK 32               // objects per pairs-tile (LDS-staged)
#define NTILE (KOBJ / TK)   // 16
#define HB 8                // hits per thread (register blocking)
#define HCH (256 * HB)      // 2048 hits per block (x-dim)
#define NTAB 8              // device-scope atomic partial tables

typedef _Float16 half2_t __attribute__((ext_vector_type(2)));

#define AGS(p, v) __hip_atomic_store((p), (v), __ATOMIC_RELAXED, __HIP_MEMORY_SCOPE_AGENT)
#define AGL(p)    __hip_atomic_load((p), __ATOMIC_RELAXED, __HIP_MEMORY_SCOPE_AGENT)

__device__ __forceinline__ float wave_red_f(float v) {
  #pragma unroll
  for (int off = 32; off > 0; off >>= 1) v += __shfl_down(v, off, 64);
  return v;
}

// fast atanh(b)^2 + 1 ; b in (0, 0.96]
__device__ __forceinline__ float q_of_beta(float b) {
  float a = 0.5f * __logf((1.f + b) / (1.f - b));
  return fmaf(a, a, 1.f);
}

// acc + y.h0*k.h0 + ... over 8 fp16 components, fp32 accumulate.
// Fixed op order -> bit-identical between in-loop and own-undo paths.
__device__ __forceinline__ float dot8h(uint4 kx, const uint* y, float acc) {
#if __has_builtin(__builtin_amdgcn_fdot2)
  acc = __builtin_amdgcn_fdot2(__builtin_bit_cast(half2_t, y[0]),
                               __builtin_bit_cast(half2_t, kx.x), acc, false);
  acc = __builtin_amdgcn_fdot2(__builtin_bit_cast(half2_t, y[1]),
                               __builtin_bit_cast(half2_t, kx.y), acc, false);
  acc = __builtin_amdgcn_fdot2(__builtin_bit_cast(half2_t, y[2]),
                               __builtin_bit_cast(half2_t, kx.z), acc, false);
  acc = __builtin_amdgcn_fdot2(__builtin_bit_cast(half2_t, y[3]),
                               __builtin_bit_cast(half2_t, kx.w), acc, false);
#else
  const uint kk[4] = {kx.x, kx.y, kx.z, kx.w};
  #pragma unroll
  for (int c = 0; c < 4; c++) {
    half2_t a = __builtin_bit_cast(half2_t, y[c]);
    half2_t b = __builtin_bit_cast(half2_t, kk[c]);
    acc = fmaf((float)a.x, (float)b.x, acc);
    acc = fmaf((float)a.y, (float)b.y, acc);
  }
#endif
  return acc;
}

// ---------------------------------------------------------------------------
// Pass 1: ceil(n/256) blocks, 1 hit/thread. No LDS table: per-object
// argmax(q)/count go straight to 8 device-scope atomic tables (zeroed by a
// memset node); ~60 atomics/address, device-coherent across XCDs. Payload
// losses block-reduced to scal_part. Also emits packed per-hit records:
//   hry[i] = 8 fp16 of (-2*x_i)      (16 B)
//   hrm[i] = { |x|^2, q, oid, 0 }    (16 B)
// ---------------------------------------------------------------------------
__global__ __launch_bounds__(256) void
k_prep(const float* __restrict__ beta, const float* __restrict__ x,
       const int* __restrict__ oid,
       const float* __restrict__ energy, const float* __restrict__ eph,
       const float* __restrict__ mom, const float* __restrict__ mph,
       const float* __restrict__ logits, const int* __restrict__ pid,
       unsigned long long* __restrict__ amax8,   // [NTAB][KOBJ]
       unsigned* __restrict__ cnt8,              // [NTAB][KOBJ]
       float* __restrict__ scal_part,
       uint4* __restrict__ hry, uint4* __restrict__ hrm, int n) {
  const int tid = threadIdx.x;
  const int i = blockIdx.x * 256 + tid;
  const int tb = blockIdx.x & (NTAB - 1);

  float e_t = 0.f, p_t = 0.f, pid_t = 0.f, noise_t = 0.f, ncnt = 0.f, mcnt = 0.f;
  if (i < n) {
    float b = beta[i];
    int o = oid[i];
    float q = q_of_beta(b);                  // needed for ALL hits (repulsion)
    const float4* xp = (const float4*)x;
    float4 xa = xp[2 * (size_t)i];
    float4 xb = xp[2 * (size_t)i + 1];
    float xi[8] = {xa.x, xa.y, xa.z, xa.w, xb.x, xb.y, xb.z, xb.w};
    float s = 0.f;
    #pragma unroll
    for (int c = 0; c < 8; c++) s = fmaf(xi[c], xi[c], s);
    uint4 r0;
    {
      half2_t h0 = { (_Float16)(-2.f * xi[0]), (_Float16)(-2.f * xi[1]) };
      half2_t h1 = { (_Float16)(-2.f * xi[2]), (_Float16)(-2.f * xi[3]) };
      half2_t h2 = { (_Float16)(-2.f * xi[4]), (_Float16)(-2.f * xi[5]) };
      half2_t h3 = { (_Float16)(-2.f * xi[6]), (_Float16)(-2.f * xi[7]) };
      r0.x = __builtin_bit_cast(uint, h0);
      r0.y = __builtin_bit_cast(uint, h1);
      r0.z = __builtin_bit_cast(uint, h2);
      r0.w = __builtin_bit_cast(uint, h3);
    }
    uint4 r1 = { __float_as_uint(s), __float_as_uint(q), (uint)o, 0u };
    hry[i] = r0;
    hrm[i] = r1;

    if (o > 0) {
      // pack (q bits | ~i): max-q wins, ties -> smallest index (argmax semantics)
      unsigned long long key = ((unsigned long long)__float_as_uint(q) << 32)
                             | (unsigned long long)(unsigned)(~(unsigned)i);
      atomicMax(&amax8[(size_t)tb * KOBJ + (o - 1)], key);
      atomicAdd(&cnt8[(size_t)tb * KOBJ + (o - 1)], 1u);
      mcnt = 1.f;
      float de = energy[i] - eph[i];
      e_t = de * de;
      float p0 = mom[3*i+0] - mph[3*i+0];
      float p1 = mom[3*i+1] - mph[3*i+1];
      float p2 = mom[3*i+2] - mph[3*i+2];
      p_t = fmaf(p0, p0, 0.f); p_t = fmaf(p1, p1, p_t); p_t = fmaf(p2, p2, p_t);
      const float2* lg2 = (const float2*)(logits + 6*i);
      float2 la = lg2[0], lb = lg2[1], lc = lg2[2];
      float l0=la.x, l1=la.y, l2=lb.x, l3=lb.y, l4=lc.x, l5=lc.y;
      float mx = fmaxf(fmaxf(fmaxf(l0,l1),fmaxf(l2,l3)), fmaxf(l4,l5));
      float sm = __expf(l0-mx)+__expf(l1-mx)+__expf(l2-mx)
               + __expf(l3-mx)+__expf(l4-mx)+__expf(l5-mx);
      int pc = pid[i];
      float lp = (pc==0)?l0:(pc==1)?l1:(pc==2)?l2:(pc==3)?l3:(pc==4)?l4:l5;
      pid_t = mx + __logf(sm) - lp;
    } else {
      noise_t = b;
      ncnt = 1.f;
    }
  }

  float vals[6] = {e_t, p_t, pid_t, noise_t, ncnt, mcnt};
  #pragma unroll
  for (int j = 0; j < 6; j++) vals[j] = wave_red_f(vals[j]);
  __shared__ float sred[4][6];
  int w = tid >> 6, l = tid & 63;
  if (l == 0) {
    #pragma unroll
    for (int j = 0; j < 6; j++) sred[w][j] = vals[j];
  }
  __syncthreads();
  if (tid == 0) {
    #pragma unroll
    for (int j = 0; j < 6; j++)
      scal_part[blockIdx.x * 8 + j] = sred[0][j]+sred[1][j]+sred[2][j]+sred[3][j];
  }
}

// ---------------------------------------------------------------------------
// Pass 2 (hot): grid (59 hit-chunks x 16 tiles = 944 blocks).
// Phase A: 256 threads = 8 tables x 32 objects; 3 KB of table reads,
// LDS 8-way reduce, build the packed 32-row fp16 tile in LDS (same formulas
// and bits as before -> own-undo stays bit-exact). Coward partials from the
// 16 blockIdx.x==0 blocks.
// Phase B: HB=8 hits/thread (precomputed records), rare wave-branch accept
// path, row prefetch. Last-finishing block finalizes (device-scope atomics).
// ---------------------------------------------------------------------------
__global__ __launch_bounds__(256, 4) void
k_pairs(const uint4* __restrict__ hry, const uint4* __restrict__ hrm,
        const unsigned long long* __restrict__ amax8,
        const unsigned* __restrict__ cnt8,
        const float* __restrict__ x, const float* __restrict__ beta,
        const float* __restrict__ scal_part, float* __restrict__ cow_part,
        float* __restrict__ pairs_part, unsigned* __restrict__ done_cnt,
        float* __restrict__ out, int n, int nprep) {
  __shared__ __align__(16) uint skt[(TK + 1) * KTW];  // 32 rows + zero pad row
  __shared__ unsigned long long skey[NTAB][TK];
  __shared__ unsigned scnt[NTAB][TK];
  __shared__ float sredu[4][10];
  __shared__ unsigned slast;
  const int tid = threadIdx.x;
  const int w = tid >> 6, l = tid & 63;
  const int tile0 = blockIdx.y * TK;
  const int hbase = blockIdx.x * HCH;
  const int nblk = gridDim.x * gridDim.y;
  const int bid = blockIdx.y * gridDim.x + blockIdx.x;

  // ---- Phase A: build the tile from the 8 atomic tables ----
  {
    const int tb = tid >> 5, ko = tid & 31;
    skey[tb][ko] = amax8[(size_t)tb * KOBJ + tile0 + ko];
    scnt[tb][ko] = cnt8[(size_t)tb * KOBJ + tile0 + ko];
    __syncthreads();
    float cowv = 0.f;
    if (tid < TK) {
      unsigned long long key = skey[0][tid];
      unsigned cnt = scnt[0][tid];
      #pragma unroll
      for (int c = 1; c < NTAB; c++) {
        unsigned long long kc = skey[c][tid];
        key = (kc > key) ? kc : key;
        cnt += scnt[c][tid];
      }
      unsigned idx = ~(unsigned)(key & 0xffffffffull);
      float q_k = __uint_as_float((unsigned)(key >> 32));
      const float4* xp4 = (const float4*)x;
      float4 xa = xp4[2 * (size_t)idx];
      float4 xb = xp4[2 * (size_t)idx + 1];
      float xv[8] = {xa.x, xa.y, xa.z, xa.w, xb.x, xb.y, xb.z, xb.w};
      float s2 = 0.f;
      #pragma unroll
      for (int c = 0; c < 8; c++) s2 = fmaf(xv[c], xv[c], s2);
      uint* kt = &skt[tid * KTW];
      #pragma unroll
      for (int c = 0; c < 4; c++) {
        half2_t hp = { (_Float16)xv[2*c], (_Float16)xv[2*c+1] };
        kt[c] = __builtin_bit_cast(uint, hp);
      }
      kt[4] = __float_as_uint(s2);
      kt[5] = __float_as_uint(q_k / ((float)(n - (int)cnt) + 1e-9f));  // w_rep
      kt[6] = __float_as_uint(q_k / ((float)cnt + 1e-9f));             // w_att
      kt[7] = 0u;
      if (blockIdx.x == 0) cowv = 1.f - beta[idx];
    }
    if (tid >= TK && tid < TK + KTW) skt[TK * KTW + (tid - TK)] = 0u;  // pad row
    if (tid < 64) {                          // wave 0: coward over the tile
      cowv = wave_red_f(cowv);
      if (tid == 0 && blockIdx.x == 0) AGS(&cow_part[blockIdx.y], cowv);
    }
    __syncthreads();
  }

  // ---- Phase B: per-hit state from packed records ----
  uint yh[HB][4];
  float thr[HB], bh[HB], qi[HB];
  int own[HB];
  #pragma unroll
  for (int h = 0; h < HB; h++) {
    int i = hbase + h * 256 + tid;
    if (i < n) {
      uint4 ra = hry[i];
      uint4 rb = hrm[i];
      yh[h][0] = ra.x; yh[h][1] = ra.y; yh[h][2] = ra.z; yh[h][3] = ra.w;
      float s = __uint_as_float(rb.x);
      bh[h] = s;
      thr[h] = 1.f - s;     // accept iff d2' < thr  (d2 = d2' + |xi|^2 < 1)
      qi[h] = __uint_as_float(rb.y);
      own[h] = (int)rb.z - 1 - tile0;
    } else {
      #pragma unroll
      for (int c = 0; c < 4; c++) yh[h][c] = 0u;
      bh[h] = 0.f;
      thr[h] = -1e30f;               // never accept
      qi[h] = 0.f;
      own[h] = -1;
    }
  }

  float att = 0.f, rep = 0.f, nrep = 0.f;
  const uint4* skt4 = (const uint4*)skt;     // row r = skt4[2r], skt4[2r+1]
  uint4 ka = skt4[0], kb = skt4[1];
  #pragma unroll 2
  for (int r = 0; r < TK; r++) {
    uint4 na = skt4[2*r + 2];                // prefetch next row (pad at r=TK-1)
    uint4 nb = skt4[2*r + 3];
    float s2 = __uint_as_float(kb.x);
    float wr = __uint_as_float(kb.y);
    float dp[HB];
    #pragma unroll
    for (int h = 0; h < HB; h++) dp[h] = dot8h(ka, yh[h], s2);  // s2 - 2*xi.xk
    bool any = false;
    #pragma unroll
    for (int h = 0; h < HB; h++) any = any | (dp[h] < thr[h]);
    if (any) {                               // wave-branch, ~5% taken
      #pragma unroll
      for (int h = 0; h < HB; h++) {
        if (dp[h] < thr[h]) {                // d2 < 1
          float d2 = dp[h] + bh[h];
          float dist = sqrtf(fmaxf(d2, 1e-12f));
          rep = fmaf(qi[h] * (1.f - dist), wr, rep);
          nrep += 1.f;
        }
      }
    }
    ka = na; kb = nb;
  }

  // own-object: attractive term + bit-exact undo of in-loop repulsive term
  #pragma unroll
  for (int h = 0; h < HB; h++) {
    int ko = own[h];
    if (ko >= 0 && ko < TK) {
      uint4 oa = skt4[2*ko];
      uint4 ob = skt4[2*ko + 1];
      float s2 = __uint_as_float(ob.x);
      float wr = __uint_as_float(ob.y);
      float wa = __uint_as_float(ob.z);
      float dp = dot8h(oa, yh[h], s2);       // identical op order -> same bits
      float d2 = dp + bh[h];
      att = fmaf(qi[h] * fmaxf(d2, 0.f), wa, att);
      if (dp < thr[h]) {
        float dist = sqrtf(fmaxf(d2, 1e-12f));
        rep = fmaf(-qi[h] * (1.f - dist), wr, rep);
        nrep -= 1.f;
      }
    }
  }

  att = wave_red_f(att);
  rep = wave_red_f(rep);
  nrep = wave_red_f(nrep);
  if (l == 0) { sredu[w][0] = att; sredu[w][1] = rep; sredu[w][2] = nrep; }
  __syncthreads();
  if (tid == 0) {
    AGS(&pairs_part[bid * 4 + 0], sredu[0][0]+sredu[1][0]+sredu[2][0]+sredu[3][0]);
    AGS(&pairs_part[bid * 4 + 1], sredu[0][1]+sredu[1][1]+sredu[2][1]+sredu[3][1]);
    AGS(&pairs_part[bid * 4 + 2], sredu[0][2]+sredu[1][2]+sredu[2][2]+sredu[3][2]);
    // release-RMW orders the scoped stores above; acquire side pairs with it
    slast = __hip_atomic_fetch_add(done_cnt, 1u, __ATOMIC_ACQ_REL,
                                   __HIP_MEMORY_SCOPE_AGENT);
  }
  __syncthreads();

  // ---- Finalize: last block only ----
  if (slast == (unsigned)(nblk - 1)) {
    float v[10] = {0,0,0,0,0,0,0,0,0,0};  // att,rep,nrep,e,p,pid,noise,ncnt,mcnt,cow
    for (int b2 = tid; b2 < nblk; b2 += 256) {
      v[0] += AGL(&pairs_part[b2 * 4 + 0]);
      v[1] += AGL(&pairs_part[b2 * 4 + 1]);
      v[2] += AGL(&pairs_part[b2 * 4 + 2]);
    }
    for (int m = tid; m < nprep; m += 256) {
      #pragma unroll
      for (int j = 0; j < 6; j++) v[3 + j] += scal_part[m * 8 + j];
    }
    for (int g = tid; g < NTILE; g += 256) v[9] += AGL(&cow_part[g]);
    #pragma unroll
    for (int j = 0; j < 10; j++) v[j] = wave_red_f(v[j]);
    __syncthreads();                      // sredu reuse
    if (l == 0) {
      #pragma unroll
      for (int j = 0; j < 10; j++) sredu[w][j] = v[j];
    }
    __syncthreads();
    if (tid == 0) {
      float t10[10];
      #pragma unroll
      for (int j = 0; j < 10; j++)
        t10[j] = sredu[0][j]+sredu[1][j]+sredu[2][j]+sredu[3][j];
      float v_att  = t10[0] / (float)KOBJ;
      float v_rep  = t10[1] / (float)KOBJ;
      float n_rep  = t10[2];
      float l_cow  = t10[9] / (float)KOBJ;
      float l_noise = t10[6] / t10[7];
      float oc = v_att + v_rep + l_cow + l_noise;
      float nm = t10[8];
      float e_loss  = t10[3] / nm;
      float p_loss  = t10[4] / (nm * 3.f);
      float pid_loss = t10[5] / nm;
      out[0] = v_att;
      out[1] = v_rep;
      out[2] = l_cow;
      out[3] = l_noise;
      out[4] = n_rep;
      out[5] = oc;
      out[6] = e_loss;
      out[7] = p_loss;
      out[8] = pid_loss;
      out[9] = oc + e_loss + p_loss + pid_loss;
    }
  }
}

extern "C" void kernel_launch(void* const* d_in, const int* in_sizes, int n_in,
                              void* d_out, int out_size, void* d_ws, size_t ws_size,
                              hipStream_t stream) {
  const float* beta   = (const float*)d_in[0];
  const float* x      = (const float*)d_in[1];
  const int*   oid    = (const int*)d_in[2];
  const float* energy = (const float*)d_in[3];
  const float* eph    = (const float*)d_in[4];
  const float* mom    = (const float*)d_in[5];
  const float* mph    = (const float*)d_in[6];
  const float* logits = (const float*)d_in[7];
  const int*   pid    = (const int*)d_in[8];
  float* outp = (float*)d_out;
  const int n = in_sizes[0];
  const int nprep = (n + 255) / 256;        // 469 prep blocks, 1 hit/thread
  const int nhb = (n + HCH - 1) / HCH;      // 59 hit-chunks
  const int nblk_tot = nhb * NTILE;         // 944

  char* base = (char*)d_ws;
  size_t off = 0;
  // --- zeroed region (single memset node) ---
  unsigned long long* amax8 = (unsigned long long*)(base + off); off += (size_t)NTAB * KOBJ * 8;
  unsigned* cnt8     = (unsigned*)(base + off);                  off += (size_t)NTAB * KOBJ * 4;
  unsigned* done_cnt = (unsigned*)(base + off);                  off += 4;
  const size_t zero_bytes = off;
  off = (off + 255) & ~(size_t)255;
  // --- write-before-read region (no zeroing needed) ---
  float* cow_part   = (float*)(base + off); off += (size_t)NTILE * 4;
  float* pairs_part = (float*)(base + off); off += (size_t)nblk_tot * 4 * 4;
  float* scal_part  = (float*)(base + off); off += (size_t)nprep * 8 * 4;
  off = (off + 255) & ~(size_t)255;
  uint4* hry = (uint4*)(base + off); off += (size_t)nprep * 256 * 16;
  uint4* hrm = (uint4*)(base + off); off += (size_t)nprep * 256 * 16;

  hipMemsetAsync(base, 0, zero_bytes, stream);
  k_prep<<<nprep, 256, 0, stream>>>(beta, x, oid, energy, eph, mom, mph, logits, pid,
                                    amax8, cnt8, scal_part, hry, hrm, n);
  k_pairs<<<dim3(nhb, NTILE), 256, 0, stream>>>(hry, hrm, amax8, cnt8, x, beta,
                                                scal_part, cow_part, pairs_part,
                                                done_cnt, outp, n, nprep);
}

// Round 7
// 119.483 us; speedup vs baseline: 1.0017x; 1.0017x over previous
//
#include <hip/hip_runtime.h>
#include <math.h>

#define KOBJ 512
#define KTW 8               // packed row (32 B): xh[4] (8 fp16), s2, w_rep, w_att, pk(1,s2)
#define TK 32               // objects per pairs-tile
#define NTILE (KOBJ / TK)   // 16
#define HCH 2048            // hits per pairs block
#define MPREP 256           // prep blocks -> partial-table rows
#define GB 64               // gather blocks (8 objects each)

typedef _Float16 half2_t __attribute__((ext_vector_type(2)));
typedef _Float16 f16x8   __attribute__((ext_vector_type(8)));
typedef float    f32x16  __attribute__((ext_vector_type(16)));

#define AGS(p, v) __hip_atomic_store((p), (v), __ATOMIC_RELAXED, __HIP_MEMORY_SCOPE_AGENT)
#define AGL(p)    __hip_atomic_load((p), __ATOMIC_RELAXED, __HIP_MEMORY_SCOPE_AGENT)

__device__ __forceinline__ float wave_red_f(float v) {
  #pragma unroll
  for (int off = 32; off > 0; off >>= 1) v += __shfl_down(v, off, 64);
  return v;
}

// fast atanh(b)^2 + 1 ; b in (0, 0.96]
__device__ __forceinline__ float q_of_beta(float b) {
  float a = 0.5f * __logf((1.f + b) / (1.f - b));
  return fmaf(a, a, 1.f);
}

// acc + y.h0*k.h0 + ... over 8 fp16 components, fp32 accumulate (att term).
__device__ __forceinline__ float dot8h(uint4 kx, const uint* y, float acc) {
#if __has_builtin(__builtin_amdgcn_fdot2)
  acc = __builtin_amdgcn_fdot2(__builtin_bit_cast(half2_t, y[0]),
                               __builtin_bit_cast(half2_t, kx.x), acc, false);
  acc = __builtin_amdgcn_fdot2(__builtin_bit_cast(half2_t, y[1]),
                               __builtin_bit_cast(half2_t, kx.y), acc, false);
  acc = __builtin_amdgcn_fdot2(__builtin_bit_cast(half2_t, y[2]),
                               __builtin_bit_cast(half2_t, kx.z), acc, false);
  acc = __builtin_amdgcn_fdot2(__builtin_bit_cast(half2_t, y[3]),
                               __builtin_bit_cast(half2_t, kx.w), acc, false);
#else
  const uint kk[4] = {kx.x, kx.y, kx.z, kx.w};
  #pragma unroll
  for (int c = 0; c < 4; c++) {
    half2_t a = __builtin_bit_cast(half2_t, y[c]);
    half2_t b = __builtin_bit_cast(half2_t, kk[c]);
    acc = fmaf((float)a.x, (float)b.x, acc);
    acc = fmaf((float)a.y, (float)b.y, acc);
  }
#endif
  return acc;
}

// ---------------------------------------------------------------------------
// Pass 1 (R5 form + hrm.w packing): 256 blocks, LDS per-object argmax/count
// tables -> partial rows; payload losses block-reduced; per-hit records:
//   hry[i] = 8 fp16 of (-2*x_i)
//   hrm[i] = { |x|^2, q, oid, pack_half2(|x|^2 - 1, 1) }
// ---------------------------------------------------------------------------
__global__ __launch_bounds__(256) void
k_prep(const float* __restrict__ beta, const float* __restrict__ x,
       const int* __restrict__ oid,
       const float* __restrict__ energy, const float* __restrict__ eph,
       const float* __restrict__ mom, const float* __restrict__ mph,
       const float* __restrict__ logits, const int* __restrict__ pid,
       unsigned long long* __restrict__ amax_part,
       unsigned* __restrict__ cnt_part,
       float* __restrict__ scal_part,
       uint4* __restrict__ hry, uint4* __restrict__ hrm,
       unsigned* __restrict__ done_cnt, int n) {
  __shared__ unsigned long long lmax[KOBJ];
  __shared__ unsigned lcnt[KOBJ];
  if (blockIdx.x == 0 && threadIdx.x == 0) *done_cnt = 0u;
  for (int t = threadIdx.x; t < KOBJ; t += 256) { lmax[t] = 0ull; lcnt[t] = 0u; }
  __syncthreads();

  const float4* xp = (const float4*)x;
  float e_t = 0.f, p_t = 0.f, pid_t = 0.f, noise_t = 0.f, ncnt = 0.f, mcnt = 0.f;
  for (int i = blockIdx.x * 256 + threadIdx.x; i < n; i += MPREP * 256) {
    float b = beta[i];
    int o = oid[i];
    float q = q_of_beta(b);
    float4 xa = xp[2 * (size_t)i];
    float4 xb = xp[2 * (size_t)i + 1];
    float xi[8] = {xa.x, xa.y, xa.z, xa.w, xb.x, xb.y, xb.z, xb.w};
    float s = 0.f;
    #pragma unroll
    for (int c = 0; c < 8; c++) s = fmaf(xi[c], xi[c], s);
    uint4 r0;
    {
      half2_t h0 = { (_Float16)(-2.f * xi[0]), (_Float16)(-2.f * xi[1]) };
      half2_t h1 = { (_Float16)(-2.f * xi[2]), (_Float16)(-2.f * xi[3]) };
      half2_t h2 = { (_Float16)(-2.f * xi[4]), (_Float16)(-2.f * xi[5]) };
      half2_t h3 = { (_Float16)(-2.f * xi[6]), (_Float16)(-2.f * xi[7]) };
      r0.x = __builtin_bit_cast(uint, h0);
      r0.y = __builtin_bit_cast(uint, h1);
      r0.z = __builtin_bit_cast(uint, h2);
      r0.w = __builtin_bit_cast(uint, h3);
    }
    half2_t hb1 = { (_Float16)(s - 1.f), (_Float16)1.f };   // augmented-K A tail
    uint4 r1 = { __float_as_uint(s), __float_as_uint(q), (uint)o,
                 __builtin_bit_cast(uint, hb1) };
    hry[i] = r0;
    hrm[i] = r1;

    if (o > 0) {
      unsigned long long key = ((unsigned long long)__float_as_uint(q) << 32)
                             | (unsigned long long)(unsigned)(~(unsigned)i);
      atomicMax(&lmax[o - 1], key);
      atomicAdd(&lcnt[o - 1], 1u);
      mcnt += 1.f;
      float de = energy[i] - eph[i];
      e_t = fmaf(de, de, e_t);
      float p0 = mom[3*i+0] - mph[3*i+0];
      float p1 = mom[3*i+1] - mph[3*i+1];
      float p2 = mom[3*i+2] - mph[3*i+2];
      p_t = fmaf(p0, p0, p_t); p_t = fmaf(p1, p1, p_t); p_t = fmaf(p2, p2, p_t);
      const float* lg = logits + 6*i;
      float l0=lg[0], l1=lg[1], l2=lg[2], l3=lg[3], l4=lg[4], l5=lg[5];
      float mx = fmaxf(fmaxf(fmaxf(l0,l1),fmaxf(l2,l3)), fmaxf(l4,l5));
      float sm = __expf(l0-mx)+__expf(l1-mx)+__expf(l2-mx)
               + __expf(l3-mx)+__expf(l4-mx)+__expf(l5-mx);
      int pc = pid[i];
      float lp = (pc==0)?l0:(pc==1)?l1:(pc==2)?l2:(pc==3)?l3:(pc==4)?l4:l5;
      pid_t += mx + __logf(sm) - lp;
    } else {
      noise_t += b;
      ncnt += 1.f;
    }
  }
  __syncthreads();

  for (int t = threadIdx.x; t < KOBJ; t += 256) {
    amax_part[(size_t)blockIdx.x * KOBJ + t] = lmax[t];
    cnt_part[(size_t)blockIdx.x * KOBJ + t]  = lcnt[t];
  }

  float vals[6] = {e_t, p_t, pid_t, noise_t, ncnt, mcnt};
  #pragma unroll
  for (int j = 0; j < 6; j++) vals[j] = wave_red_f(vals[j]);
  __shared__ float sred[4][6];
  int w = threadIdx.x >> 6, l = threadIdx.x & 63;
  if (l == 0) {
    #pragma unroll
    for (int j = 0; j < 6; j++) sred[w][j] = vals[j];
  }
  __syncthreads();
  if (threadIdx.x == 0) {
    #pragma unroll
    for (int j = 0; j < 6; j++)
      scal_part[blockIdx.x * 8 + j] = sred[0][j]+sred[1][j]+sred[2][j]+sred[3][j];
  }
}

// ---------------------------------------------------------------------------
// Pass 2 (R5 form + kt[7] packing): 64 blocks, reduce partial rows once into
// ktab[512][8] + coward partials. kt[7] = pack_half2(1, s2) (augmented-K B).
// ---------------------------------------------------------------------------
__global__ __launch_bounds__(256) void
k_gather(const float* __restrict__ x, const float* __restrict__ beta,
         const unsigned long long* __restrict__ amax_part,
         const unsigned* __restrict__ cnt_part,
         uint* __restrict__ ktab, float* __restrict__ cow_part, int n) {
  __shared__ unsigned long long skey[32][8];
  __shared__ unsigned scnt[32][8];
  const int o = threadIdx.x & 7, seg = threadIdx.x >> 3;
  const int k = blockIdx.x * 8 + o;

  unsigned long long key = 0ull;
  unsigned cnt = 0u;
  for (int m = seg; m < MPREP; m += 32) {
    unsigned long long km = amax_part[(size_t)m * KOBJ + k];
    key = (km > key) ? km : key;
    cnt += cnt_part[(size_t)m * KOBJ + k];
  }
  skey[seg][o] = key;
  scnt[seg][o] = cnt;
  __syncthreads();
  for (int s = 16; s > 0; s >>= 1) {
    if (seg < s) {
      unsigned long long k2 = skey[seg + s][o];
      if (k2 > skey[seg][o]) skey[seg][o] = k2;
      scnt[seg][o] += scnt[seg + s][o];
    }
    __syncthreads();
  }

  float cowv = 0.f;
  if (threadIdx.x < 8) {
    key = skey[0][o];
    cnt = scnt[0][o];
    unsigned idx = ~(unsigned)(key & 0xffffffffull);
    float q_k = __uint_as_float((unsigned)(key >> 32));
    const float4* xp = (const float4*)x;
    float4 xa = xp[2 * (size_t)idx];
    float4 xb = xp[2 * (size_t)idx + 1];
    float xv[8] = {xa.x, xa.y, xa.z, xa.w, xb.x, xb.y, xb.z, xb.w};
    float s2 = 0.f;
    #pragma unroll
    for (int c = 0; c < 8; c++) s2 = fmaf(xv[c], xv[c], s2);
    uint* kt = ktab + (size_t)k * KTW;
    #pragma unroll
    for (int c = 0; c < 4; c++) {
      half2_t hp = { (_Float16)xv[2*c], (_Float16)xv[2*c+1] };
      kt[c] = __builtin_bit_cast(uint, hp);
    }
    kt[4] = __float_as_uint(s2);
    kt[5] = __float_as_uint(q_k / ((float)(n - (int)cnt) + 1e-9f));  // w_rep
    kt[6] = __float_as_uint(q_k / ((float)cnt + 1e-9f));             // w_att
    half2_t h1s = { (_Float16)1.f, (_Float16)s2 };                   // (1, s2)
    kt[7] = __builtin_bit_cast(uint, h1s);
    cowv = 1.f - beta[idx];
  }
  if (threadIdx.x < 64) {
    cowv = wave_red_f(cowv);
    if (threadIdx.x == 0) cow_part[blockIdx.x] = cowv;
  }
}

// ---------------------------------------------------------------------------
// Pass 3 (hot, MFMA): grid (59 chunks x 16 tiles). Block = 2048 hits x 32
// centers. Augmented K=10 GEMM: A row = [y(8), bh-1, 1], B col = [x(8), 1,
// s2] so acc t = d2 - 1; accept iff t < 0. Per wave: 16 mfma 32x32x16_f16
// per tile; fast path = fminf tree + __any branch; slow path (rare) reads
// qi/oid from global and SKIPS own pairs (no undo needed). Attractive term
// in the per-thread own-loop (fp32 dot8h), unchanged. Last-block finalize.
// ---------------------------------------------------------------------------
__global__ __launch_bounds__(256, 3) void
k_pairs(const uint4* __restrict__ hry, const uint4* __restrict__ hrm,
        const uint* __restrict__ ktab,
        const float* __restrict__ scal_part, const float* __restrict__ cow_part,
        float* __restrict__ pairs_part, unsigned* __restrict__ done_cnt,
        float* __restrict__ out, int n) {
  __shared__ __align__(16) uint4 yls[HCH];      // 32 KiB: y fp16 rows
  __shared__ uint bh1s[HCH];                    // 8 KiB: packed (bh-1, 1)
  __shared__ __align__(16) uint skt[TK * KTW];  // 1 KiB center tile
  __shared__ float sredu[4][10];
  __shared__ unsigned slast;

  const int tid = threadIdx.x;
  const int w = tid >> 6, l = tid & 63;
  const int tile0 = blockIdx.y * TK;
  const int hbase = blockIdx.x * HCH;
  const int nblk = gridDim.x * gridDim.y;
  const int bid = blockIdx.y * gridDim.x + blockIdx.x;

  skt[tid] = ktab[(size_t)tile0 * KTW + tid];   // 256 words = whole tile

  // stage y + bh1 to LDS; keep this thread's 8 records for the att loop
  uint4 yl[8];
  float bhv[8], qv[8];
  int ov[8];
  #pragma unroll
  for (int j = 0; j < 8; j++) {
    int il = j * 256 + tid;
    int i = hbase + il;
    uint4 ry, rm;
    if (i < n) {
      ry = hry[i];
      rm = hrm[i];
    } else {
      ry = (uint4){0u, 0u, 0u, 0u};
      half2_t sent = { (_Float16)60000.f, (_Float16)0.f };  // t=60000 -> never accept
      rm = (uint4){0u, 0u, 0u, __builtin_bit_cast(uint, sent)};
    }
    yls[il] = ry;
    bh1s[il] = rm.w;
    yl[j] = ry;
    bhv[j] = __uint_as_float(rm.x);
    qv[j] = __uint_as_float(rm.y);
    ov[j] = (int)rm.z - 1;
  }
  __syncthreads();

  // per-lane center data (col = lane&31 for all C regs)
  const int col = l & 31;
  uint4 bfr;
  if (l < 32) bfr = *(const uint4*)&skt[col * KTW];            // x fp16 x8 (k=0..7)
  else        bfr = (uint4){skt[col * KTW + 7], 0u, 0u, 0u};   // (1, s2) (k=8..15)
  const float wr = __uint_as_float(skt[col * KTW + 5]);
  const int cglob = tile0 + col;
  const f16x8 Bf = __builtin_bit_cast(f16x8, bfr);
  const f32x16 zc = {0.f,0.f,0.f,0.f,0.f,0.f,0.f,0.f,
                     0.f,0.f,0.f,0.f,0.f,0.f,0.f,0.f};

  float att = 0.f, rep = 0.f, nrep = 0.f;
  for (int hb = w * 16; hb < w * 16 + 16; hb++) {
    const int rbase = hb * 32;
    uint4 afr;
    if (l < 32) afr = yls[rbase + col];                          // y row (k=0..7)
    else        afr = (uint4){bh1s[rbase + col], 0u, 0u, 0u};    // (bh-1, 1)
    f32x16 acc = __builtin_amdgcn_mfma_f32_32x32x16_f16(
        __builtin_bit_cast(f16x8, afr), Bf, zc, 0, 0, 0);

    float m = acc[0];
    #pragma unroll
    for (int r2 = 1; r2 < 16; r2++) m = fminf(m, acc[r2]);
    if (__any(m < 0.f)) {                    // rare: any accepted pair in 1024
      #pragma unroll
      for (int reg = 0; reg < 16; reg++) {
        float t = acc[reg];
        if (t < 0.f) {                       // d2 < 1
          int row = (reg & 3) + 8 * (reg >> 2) + 4 * (l >> 5);
          uint4 hv = hrm[hbase + rbase + row];      // tail rows never reach here
          float d2 = t + 1.f;
          float dist = sqrtf(fmaxf(d2, 1e-12f));
          if ((int)hv.z - 1 != cglob) {             // skip own pair
            rep = fmaf(__uint_as_float(hv.y) * (1.f - dist), wr, rep);
            nrep += 1.f;
          }
        }
      }
    }
  }

  // attractive term: this thread's 8 hits vs their own center (if in tile)
  #pragma unroll
  for (int h = 0; h < 8; h++) {
    int ko = ov[h] - tile0;
    if (ko >= 0 && ko < TK) {
      const uint* kr = &skt[ko * KTW];
      uint4 kx = *(const uint4*)kr;
      float s2 = __uint_as_float(kr[4]);
      float wa = __uint_as_float(kr[6]);
      uint yy[4] = {yl[h].x, yl[h].y, yl[h].z, yl[h].w};
      float dp = dot8h(kx, yy, s2);
      float d2 = dp + bhv[h];
      att = fmaf(qv[h] * fmaxf(d2, 0.f), wa, att);
    }
  }

  att = wave_red_f(att);
  rep = wave_red_f(rep);
  nrep = wave_red_f(nrep);
  if (l == 0) { sredu[w][0] = att; sredu[w][1] = rep; sredu[w][2] = nrep; }
  __syncthreads();
  if (tid == 0) {
    AGS(&pairs_part[bid * 4 + 0], sredu[0][0]+sredu[1][0]+sredu[2][0]+sredu[3][0]);
    AGS(&pairs_part[bid * 4 + 1], sredu[0][1]+sredu[1][1]+sredu[2][1]+sredu[3][1]);
    AGS(&pairs_part[bid * 4 + 2], sredu[0][2]+sredu[1][2]+sredu[2][2]+sredu[3][2]);
    slast = __hip_atomic_fetch_add(done_cnt, 1u, __ATOMIC_ACQ_REL,
                                   __HIP_MEMORY_SCOPE_AGENT);
  }
  __syncthreads();

  // ---- Finalize: last block only ----
  if (slast == (unsigned)(nblk - 1)) {
    float v[10] = {0,0,0,0,0,0,0,0,0,0};  // att,rep,nrep,e,p,pid,noise,ncnt,mcnt,cow
    for (int b2 = tid; b2 < nblk; b2 += 256) {
      v[0] += AGL(&pairs_part[b2 * 4 + 0]);
      v[1] += AGL(&pairs_part[b2 * 4 + 1]);
      v[2] += AGL(&pairs_part[b2 * 4 + 2]);
    }
    for (int m2 = tid; m2 < MPREP; m2 += 256) {
      #pragma unroll
      for (int j = 0; j < 6; j++) v[3 + j] += scal_part[m2 * 8 + j];
    }
    for (int g = tid; g < GB; g += 256) v[9] += cow_part[g];
    #pragma unroll
    for (int j = 0; j < 10; j++) v[j] = wave_red_f(v[j]);
    __syncthreads();
    if (l == 0) {
      #pragma unroll
      for (int j = 0; j < 10; j++) sredu[w][j] = v[j];
    }
    __syncthreads();
    if (tid == 0) {
      float t10[10];
      #pragma unroll
      for (int j = 0; j < 10; j++)
        t10[j] = sredu[0][j]+sredu[1][j]+sredu[2][j]+sredu[3][j];
      float v_att  = t10[0] / (float)KOBJ;
      float v_rep  = t10[1] / (float)KOBJ;
      float n_rep  = t10[2];
      float l_cow  = t10[9] / (float)KOBJ;
      float l_noise = t10[6] / t10[7];
      float oc = v_att + v_rep + l_cow + l_noise;
      float nm = t10[8];
      float e_loss  = t10[3] / nm;
      float p_loss  = t10[4] / (nm * 3.f);
      float pid_loss = t10[5] / nm;
      out[0] = v_att;
      out[1] = v_rep;
      out[2] = l_cow;
      out[3] = l_noise;
      out[4] = n_rep;
      out[5] = oc;
      out[6] = e_loss;
      out[7] = p_loss;
      out[8] = pid_loss;
      out[9] = oc + e_loss + p_loss + pid_loss;
    }
  }
}

extern "C" void kernel_launch(void* const* d_in, const int* in_sizes, int n_in,
                              void* d_out, int out_size, void* d_ws, size_t ws_size,
                              hipStream_t stream) {
  const float* beta   = (const float*)d_in[0];
  const float* x      = (const float*)d_in[1];
  const int*   oid    = (const int*)d_in[2];
  const float* energy = (const float*)d_in[3];
  const float* eph    = (const float*)d_in[4];
  const float* mom    = (const float*)d_in[5];
  const float* mph    = (const float*)d_in[6];
  const float* logits = (const float*)d_in[7];
  const int*   pid    = (const int*)d_in[8];
  float* outp = (float*)d_out;
  const int n = in_sizes[0];
  const int nhb = (n + HCH - 1) / HCH;      // 59 hit-chunks
  const int nblk_tot = nhb * NTILE;         // 944

  char* base = (char*)d_ws;
  size_t off = 0;
  uint*  ktab       = (uint*)(base + off);  off += (size_t)KOBJ * KTW * 4;
  float* cow_part   = (float*)(base + off); off += (size_t)GB * 4;
  float* pairs_part = (float*)(base + off); off += (size_t)nblk_tot * 4 * 4;
  float* scal_part  = (float*)(base + off); off += (size_t)MPREP * 8 * 4;
  unsigned* done_cnt = (unsigned*)(base + off); off += 256;
  off = (off + 255) & ~(size_t)255;
  unsigned long long* amax_part = (unsigned long long*)(base + off); off += (size_t)MPREP * KOBJ * 8;
  unsigned* cnt_part = (unsigned*)(base + off);                      off += (size_t)MPREP * KOBJ * 4;
  off = (off + 255) & ~(size_t)255;
  uint4* hry = (uint4*)(base + off); off += (size_t)nhb * HCH * 16;
  uint4* hrm = (uint4*)(base + off); off += (size_t)nhb * HCH * 16;

  k_prep<<<MPREP, 256, 0, stream>>>(beta, x, oid, energy, eph, mom, mph, logits, pid,
                                    amax_part, cnt_part, scal_part, hry, hrm,
                                    done_cnt, n);
  k_gather<<<GB, 256, 0, stream>>>(x, beta, amax_part, cnt_part, ktab, cow_part, n);
  k_pairs<<<dim3(nhb, NTILE), 256, 0, stream>>>(hry, hrm, ktab, scal_part, cow_part,
                                                pairs_part, done_cnt, outp, n);
}